// Round 7
// baseline (217.094 us; speedup 1.0000x reference)
//
#include <hip/hip_runtime.h>

// Problem dims
#define NN 128
#define MM 2048
#define EPSF 0.01f

typedef __bf16 bf16x8 __attribute__((ext_vector_type(8)));
typedef __bf16 bf16x4 __attribute__((ext_vector_type(4)));
typedef float  f32x4  __attribute__((ext_vector_type(4)));

// Workspace layout (float offsets), total 429184 floats = 1.72 MB
#define WS_SLACK 0            // [n][m] fp32
#define WS_W2    262144       // [n][256] fp32 gz2*softplus(Wz2)
#define WS_GZ1   294912       // [n][256] fp32
#define WS_YV    327680       // [n][8]  fp32 Y - gy2*Wy2
#define WS_CU2   328704       // [n] fp32 (pad to 128)
#define WS_WTB   328832       // bf16 [256 k][256 z] = softplus(Wz1)
#define WS_U1    361600       // bf16 [128 n][256]
#define WS_U2    377984       // bf16 [128 n][256]
#define WS_C0    394368       // bf16 [128 n][256]
#define WS_C1    410752       // bf16 [128 n][256]
#define WS_GY0   427136       // fp32 [128 n][8]
#define WS_GY1   428160       // fp32 [128 n][8]

__device__ __forceinline__ float softplusf(float x) {
    return x > 20.f ? x : log1pf(expf(x));
}

__device__ __forceinline__ bf16x8 ld_cvt8(const float* __restrict__ p) {
    const float4* p4 = (const float4*)p;
    float4 a = p4[0], b = p4[1];
    bf16x8 r;
    r[0] = (__bf16)a.x; r[1] = (__bf16)a.y; r[2] = (__bf16)a.z; r[3] = (__bf16)a.w;
    r[4] = (__bf16)b.x; r[5] = (__bf16)b.y; r[6] = (__bf16)b.z; r[7] = (__bf16)b.w;
    return r;
}

// ---------------------------------------------------------------------------
// k_s1: level 1 (K=64 over X) + WTB prep.
// blockIdx.x < 9: 33 col-tiles: [0,16)=Wt0->u1, [16,32)=Wu0->c0, 32=Wyu0->gy0
// blockIdx.x in [9, 73): WTB[k][z] = bf16(softplus(Wz1[k][z])) (y==0 only)
// ---------------------------------------------------------------------------
__global__ __launch_bounds__(256) void k_s1(
    const float* __restrict__ X,
    const float* __restrict__ Wt0, const float* __restrict__ bt0,
    const float* __restrict__ Wu0, const float* __restrict__ b0,
    const float* __restrict__ Wyu0, const float* __restrict__ byu0,
    const float* __restrict__ Wz1,
    float* __restrict__ ws)
{
    const int t = threadIdx.x, bx = blockIdx.x;
    if (bx >= 9) {
        if (blockIdx.y != 0) return;
        const int i = (bx - 9) * 1024 + t * 4;
        float4 v = *(const float4*)(Wz1 + i);
        bf16x4 r;
        r[0] = (__bf16)softplusf(v.x); r[1] = (__bf16)softplusf(v.y);
        r[2] = (__bf16)softplusf(v.z); r[3] = (__bf16)softplusf(v.w);
        *(bf16x4*)((__bf16*)(ws + WS_WTB) + i) = r;
        return;
    }
    const int w = t >> 6, lane = t & 63;
    const int c = lane & 15, q = lane >> 4;
    const int nb = blockIdx.y * 16;
    const int ct = bx * 4 + w;
    if (ct >= 33) return;

    bf16x8 a1[2];
#pragma unroll
    for (int ch = 0; ch < 2; ++ch)
        a1[ch] = ld_cvt8(X + (nb + c) * 64 + ch * 32 + q * 8);

    const float* rp;
    int col;
    if (ct < 16)      { col = ct * 16 + c;        rp = Wt0 + col * 64; }
    else if (ct < 32) { col = (ct - 16) * 16 + c; rp = Wu0 + col * 64; }
    else              { col = c & 7;              rp = Wyu0 + col * 64; }

    f32x4 D = {0.f, 0.f, 0.f, 0.f};
#pragma unroll
    for (int ch = 0; ch < 2; ++ch) {
        bf16x8 b = ld_cvt8(rp + ch * 32 + q * 8);
        D = __builtin_amdgcn_mfma_f32_16x16x32_bf16(a1[ch], b, D, 0, 0, 0);
    }

    if (ct < 16) {
        __bf16* u1p = (__bf16*)(ws + WS_U1);
        const float bv = bt0[col];
#pragma unroll
        for (int r = 0; r < 4; ++r)
            u1p[(nb + 4 * q + r) * 256 + col] = (__bf16)fmaxf(D[r] + bv, 0.f);
    } else if (ct < 32) {
        __bf16* c0p = (__bf16*)(ws + WS_C0);
        const float bv = b0[col];
#pragma unroll
        for (int r = 0; r < 4; ++r)
            c0p[(nb + 4 * q + r) * 256 + col] = (__bf16)(D[r] + bv);
    } else if (c < 8) {
        const float bv = byu0[c];
#pragma unroll
        for (int r = 0; r < 4; ++r)
            ws[WS_GY0 + (nb + 4 * q + r) * 8 + c] = D[r] + bv;
    }
}

// ---------------------------------------------------------------------------
// k_s2: level 2, K=256 over u1 (bf16). 49 tiles: Wt1->u2 | Wzu1->gz1 | Wu1->c1 | Wyu1->gy1
// ---------------------------------------------------------------------------
__global__ __launch_bounds__(256) void k_s2(
    const float* __restrict__ Wt1, const float* __restrict__ bt1,
    const float* __restrict__ Wzu1, const float* __restrict__ bzu1,
    const float* __restrict__ Wu1, const float* __restrict__ b1,
    const float* __restrict__ Wyu1, const float* __restrict__ byu1,
    float* __restrict__ ws)
{
    const int t = threadIdx.x, w = t >> 6, lane = t & 63;
    const int c = lane & 15, q = lane >> 4;
    const int nb = blockIdx.y * 16;
    const int ct = blockIdx.x * 4 + w;
    if (ct >= 49) return;

    const __bf16* u1p = (const __bf16*)(ws + WS_U1);
    bf16x8 aF[8];
#pragma unroll
    for (int ch = 0; ch < 8; ++ch)
        aF[ch] = *(const bf16x8*)(u1p + (nb + c) * 256 + ch * 32 + q * 8);

    const float* rp;
    int col;
    if (ct < 16)      { col = ct * 16 + c;        rp = Wt1 + col * 256; }
    else if (ct < 32) { col = (ct - 16) * 16 + c; rp = Wzu1 + col * 256; }
    else if (ct < 48) { col = (ct - 32) * 16 + c; rp = Wu1 + col * 256; }
    else              { col = c & 7;              rp = Wyu1 + col * 256; }

    f32x4 D = {0.f, 0.f, 0.f, 0.f};
#pragma unroll
    for (int ch = 0; ch < 8; ++ch) {
        bf16x8 b = ld_cvt8(rp + ch * 32 + q * 8);
        D = __builtin_amdgcn_mfma_f32_16x16x32_bf16(aF[ch], b, D, 0, 0, 0);
    }

    if (ct < 16) {
        __bf16* u2p = (__bf16*)(ws + WS_U2);
        const float bv = bt1[col];
#pragma unroll
        for (int r = 0; r < 4; ++r)
            u2p[(nb + 4 * q + r) * 256 + col] = (__bf16)fmaxf(D[r] + bv, 0.f);
    } else if (ct < 32) {
        const float bv = bzu1[col];
#pragma unroll
        for (int r = 0; r < 4; ++r)
            ws[WS_GZ1 + (nb + 4 * q + r) * 256 + col] = fmaxf(D[r] + bv, 0.f);
    } else if (ct < 48) {
        __bf16* c1p = (__bf16*)(ws + WS_C1);
        const float bv = b1[col];
#pragma unroll
        for (int r = 0; r < 4; ++r)
            c1p[(nb + 4 * q + r) * 256 + col] = (__bf16)(D[r] + bv);
    } else if (c < 8) {
        const float bv = byu1[c];
#pragma unroll
        for (int r = 0; r < 4; ++r)
            ws[WS_GY1 + (nb + 4 * q + r) * 8 + c] = D[r] + bv;
    }
}

// ---------------------------------------------------------------------------
// k_s3: level 3, K=256 over u2 (bf16). 17 tiles: Wzu2->w2 | (Wyu2->yv, Wu2->cu2)
// ---------------------------------------------------------------------------
__global__ __launch_bounds__(256) void k_s3(
    const float* __restrict__ Y,
    const float* __restrict__ Wzu2, const float* __restrict__ bzu2,
    const float* __restrict__ Wz2,
    const float* __restrict__ Wyu2, const float* __restrict__ byu2,
    const float* __restrict__ Wy2,
    const float* __restrict__ Wu2, const float* __restrict__ b2,
    float* __restrict__ ws)
{
    const int t = threadIdx.x, w = t >> 6, lane = t & 63;
    const int c = lane & 15, q = lane >> 4;
    const int nb = blockIdx.y * 16;
    const int ct = blockIdx.x * 4 + w;
    if (ct >= 17) return;

    const __bf16* u2p = (const __bf16*)(ws + WS_U2);
    bf16x8 aF[8];
#pragma unroll
    for (int ch = 0; ch < 8; ++ch)
        aF[ch] = *(const bf16x8*)(u2p + (nb + c) * 256 + ch * 32 + q * 8);

    const float* rp;
    int col = 0;
    if (ct < 16) { col = ct * 16 + c; rp = Wzu2 + col * 256; }
    else         { rp = (c < 8) ? (Wyu2 + c * 256) : Wu2; }

    f32x4 D = {0.f, 0.f, 0.f, 0.f};
#pragma unroll
    for (int ch = 0; ch < 8; ++ch) {
        bf16x8 b = ld_cvt8(rp + ch * 32 + q * 8);
        D = __builtin_amdgcn_mfma_f32_16x16x32_bf16(aF[ch], b, D, 0, 0, 0);
    }

    if (ct < 16) {
        const float bv = bzu2[col];
        const float sp = softplusf(Wz2[col]);
#pragma unroll
        for (int r = 0; r < 4; ++r) {
            float gz2 = fmaxf(D[r] + bv, 0.f);
            ws[WS_W2 + (nb + 4 * q + r) * 256 + col] = gz2 * sp;
        }
    } else if (c < 8) {
        const float bv = byu2[c];
        const float wy2 = Wy2[c];
#pragma unroll
        for (int r = 0; r < 4; ++r) {
            const int n = nb + 4 * q + r;
            ws[WS_YV + n * 8 + c] = Y[n * 8 + c] - (D[r] + bv) * wy2;
        }
    } else if (c == 8) {
#pragma unroll
        for (int r = 0; r < 4; ++r)
            ws[WS_CU2 + nb + 4 * q + r] = D[r] + b2[0];
    }
}

// ---------------------------------------------------------------------------
// k_main: on-the-fly B2/BX fragments (no 4 MB scratch), register
// double-buffered WTB chunk loads for latency hiding.
// ---------------------------------------------------------------------------
__global__ __launch_bounds__(256, 3) void k_main(
    const float* __restrict__ U,
    const float* __restrict__ Wy0,
    const float* __restrict__ Wy1,
    float* __restrict__ ws)
{
    __shared__ __bf16 zh[64][264];   // +8 pad
    __shared__ float gz1s[256];
    __shared__ float w2s[256];
    __shared__ float sdot[64];
    __shared__ float psum[4][64];

    const int t  = threadIdx.x;
    const int n  = blockIdx.y;
    const int m0 = blockIdx.x * 64;
    const int w    = t >> 6;
    const int lane = t & 63;
    const int c = lane & 15;
    const int q = lane >> 4;

    gz1s[t] = ws[WS_GZ1 + n * 256 + t];   // read back intra-wave only (pre-GEMM)
    w2s[t]  = ws[WS_W2  + n * 256 + t];   // read after barrier
    if (t < 64) {
        float sd = 0.f;
#pragma unroll
        for (int d = 0; d < 8; ++d)
            sd += U[(m0 + t) * 8 + d] * ws[WS_YV + n * 8 + d];
        sdot[t] = sd;
    }

    const __bf16* c0p = (const __bf16*)(ws + WS_C0) + n * 256;
    const __bf16* c1p = (const __bf16*)(ws + WS_C1) + n * 256;
    const __bf16* WTp = (const __bf16*)(ws + WS_WTB);

    // per-lane gy0/gy1 (32 B each, L2-hot)
    float g0[8], g1[8];
    {
        const float4* p0 = (const float4*)(ws + WS_GY0 + n * 8);
        const float4* p1 = (const float4*)(ws + WS_GY1 + n * 8);
        float4 a = p0[0], b = p0[1];
        g0[0]=a.x; g0[1]=a.y; g0[2]=a.z; g0[3]=a.w; g0[4]=b.x; g0[5]=b.y; g0[6]=b.z; g0[7]=b.w;
        a = p1[0]; b = p1[1];
        g1[0]=a.x; g1[1]=a.y; g1[2]=a.z; g1[3]=a.w; g1[4]=b.x; g1[5]=b.y; g1[6]=b.z; g1[7]=b.w;
    }

    // A2 frags [U | 1 | 0...]: rows m = m0 + c + 16mi
    bf16x8 a2f[4];
#pragma unroll
    for (int mi = 0; mi < 4; ++mi) {
        const float4* up = (const float4*)(U + (m0 + c + 16 * mi) * 8);
        float4 u0 = up[0], u1 = up[1];
        float uv[8] = {u0.x, u0.y, u0.z, u0.w, u1.x, u1.y, u1.z, u1.w};
#pragma unroll
        for (int j = 0; j < 8; ++j)
            a2f[mi][j] = (q == 0) ? (__bf16)uv[j] : (__bf16)0.f;
        if (q == 1) a2f[mi][0] = (__bf16)1.f;
    }

    // ---- pre-GEMM: D1[z][m], wave w covers z in [64w, 64w+64) ----
#pragma unroll
    for (int zt = 0; zt < 4; ++zt) {
        const int z = 64 * w + 16 * zt + c;
        const float4* wy = (const float4*)(Wy0 + z * 8);
        float4 wa = wy[0], wb = wy[1];
        float wv[8] = {wa.x, wa.y, wa.z, wa.w, wb.x, wb.y, wb.z, wb.w};
        const float c0v = (float)c0p[z];
        bf16x8 b2f;
#pragma unroll
        for (int j = 0; j < 8; ++j)
            b2f[j] = (q == 0) ? (__bf16)(g0[j] * wv[j]) : (__bf16)0.f;
        if (q == 1) b2f[0] = (__bf16)c0v;

        f32x4 pr[4];
#pragma unroll
        for (int mi = 0; mi < 4; ++mi) {
            f32x4 zacc = {0.f, 0.f, 0.f, 0.f};
            pr[mi] = __builtin_amdgcn_mfma_f32_16x16x32_bf16(b2f, a2f[mi], zacc, 0, 0, 0);
        }
        const int zb = 64 * w + 16 * zt + 4 * q;
#pragma unroll
        for (int mi = 0; mi < 4; ++mi) {
            bf16x4 v4;
#pragma unroll
            for (int r = 0; r < 4; ++r)
                v4[r] = (__bf16)(fmaxf(pr[mi][r], 0.f) * gz1s[zb + r]);
            *(bf16x4*)&zh[c + 16 * mi][zb] = v4;
        }
    }

    // ---- main GEMM: D2[m][k], wave w covers k in [64w, 64w+64) ----
    f32x4 acc[4][4];
#pragma unroll
    for (int mi = 0; mi < 4; ++mi)
#pragma unroll
        for (int kj = 0; kj < 4; ++kj)
            acc[mi][kj] = f32x4{0.f, 0.f, 0.f, 0.f};

    __syncthreads();

    // register double-buffer on the WTB chunk loads
    bf16x8 bwA[4], bwB[4];
#pragma unroll
    for (int kj = 0; kj < 4; ++kj)
        bwA[kj] = *(const bf16x8*)(WTp + (64 * w + 16 * kj + c) * 256 + q * 8);

#pragma unroll
    for (int ch = 0; ch < 8; ++ch) {
        bf16x8* curb = (ch & 1) ? bwB : bwA;
        bf16x8* nxtb = (ch & 1) ? bwA : bwB;
        if (ch < 7) {
#pragma unroll
            for (int kj = 0; kj < 4; ++kj)
                nxtb[kj] = *(const bf16x8*)(WTp + (64 * w + 16 * kj + c) * 256 +
                                            (ch + 1) * 32 + q * 8);
        }
        bf16x8 az[4];
#pragma unroll
        for (int mi = 0; mi < 4; ++mi)
            az[mi] = *(const bf16x8*)&zh[c + 16 * mi][ch * 32 + q * 8];
#pragma unroll
        for (int mi = 0; mi < 4; ++mi)
#pragma unroll
            for (int kj = 0; kj < 4; ++kj)
                acc[mi][kj] = __builtin_amdgcn_mfma_f32_16x16x32_bf16(
                    az[mi], curb[kj], acc[mi][kj], 0, 0, 0);
    }

    // rank-1 chunk: [U|1] x [gy1*Wy1 | c1], fragments built on the fly
#pragma unroll
    for (int kj = 0; kj < 4; ++kj) {
        const int k = 64 * w + 16 * kj + c;
        const float4* wy = (const float4*)(Wy1 + k * 8);
        float4 wa = wy[0], wb = wy[1];
        float wv[8] = {wa.x, wa.y, wa.z, wa.w, wb.x, wb.y, wb.z, wb.w};
        const float c1v = (float)c1p[k];
        bf16x8 bx;
#pragma unroll
        for (int j = 0; j < 8; ++j)
            bx[j] = (q == 0) ? (__bf16)(g1[j] * wv[j]) : (__bf16)0.f;
        if (q == 1) bx[0] = (__bf16)c1v;
#pragma unroll
        for (int mi = 0; mi < 4; ++mi)
            acc[mi][kj] = __builtin_amdgcn_mfma_f32_16x16x32_bf16(
                a2f[mi], bx, acc[mi][kj], 0, 0, 0);
    }

    // ---- epilogue: p[m] = sum_k relu(acc)*w2[k] ----
    float p[4][4];
#pragma unroll
    for (int mi = 0; mi < 4; ++mi)
#pragma unroll
        for (int r = 0; r < 4; ++r) p[mi][r] = 0.f;
#pragma unroll
    for (int kj = 0; kj < 4; ++kj) {
        float w2v = w2s[64 * w + 16 * kj + c];
#pragma unroll
        for (int mi = 0; mi < 4; ++mi)
#pragma unroll
            for (int r = 0; r < 4; ++r)
                p[mi][r] += fmaxf(acc[mi][kj][r], 0.f) * w2v;
    }
#pragma unroll
    for (int mi = 0; mi < 4; ++mi)
#pragma unroll
        for (int r = 0; r < 4; ++r) {
            float v = p[mi][r];
            v += __shfl_xor(v, 8);
            v += __shfl_xor(v, 4);
            v += __shfl_xor(v, 2);
            v += __shfl_xor(v, 1);
            p[mi][r] = v;
        }
    if (c == 0) {
#pragma unroll
        for (int mi = 0; mi < 4; ++mi)
            *(float4*)&psum[w][16 * mi + 4 * q] =
                make_float4(p[mi][0], p[mi][1], p[mi][2], p[mi][3]);
    }
    __syncthreads();
    if (t < 64) {
        float cu2 = ws[WS_CU2 + n];
        float pp = psum[0][t] + psum[1][t] + psum[2][t] + psum[3][t];
        ws[WS_SLACK + n * 2048 + m0 + t] = sdot[t] - cu2 - pp;
    }
}

// ---------------------------------------------------------------------------
// k_lse: per-n stable logsumexp over m -> psi[n]
// ---------------------------------------------------------------------------
__global__ __launch_bounds__(256) void k_lse(const float* __restrict__ ws,
                                             float* __restrict__ out) {
    __shared__ float redmax[4];
    __shared__ float redsum[4];
    const int n = blockIdx.x;
    const int t = threadIdx.x;
    const float* s = ws + WS_SLACK + n * 2048;

    float vals[8];
    float mx = -3.4e38f;
#pragma unroll
    for (int i = 0; i < 8; ++i) {
        vals[i] = s[t + 256 * i];
        mx = fmaxf(mx, vals[i]);
    }
#pragma unroll
    for (int off = 32; off; off >>= 1) mx = fmaxf(mx, __shfl_xor(mx, off));
    if ((t & 63) == 0) redmax[t >> 6] = mx;
    __syncthreads();
    mx = fmaxf(fmaxf(redmax[0], redmax[1]), fmaxf(redmax[2], redmax[3]));

    float sum = 0.f;
#pragma unroll
    for (int i = 0; i < 8; ++i) sum += expf((vals[i] - mx) * (1.f / EPSF));
#pragma unroll
    for (int off = 32; off; off >>= 1) sum += __shfl_xor(sum, off);
    if ((t & 63) == 0) redsum[t >> 6] = sum;
    __syncthreads();
    if (t == 0) {
        float S = redsum[0] + redsum[1] + redsum[2] + redsum[3];
        out[n] = EPSF * logf(S * (1.f / 2048.f)) + mx;
    }
}

// ---------------------------------------------------------------------------
extern "C" void kernel_launch(void* const* d_in, const int* in_sizes, int n_in,
                              void* d_out, int out_size, void* d_ws, size_t ws_size,
                              hipStream_t stream) {
    const float* X    = (const float*)d_in[0];
    const float* Uu   = (const float*)d_in[1];
    const float* Yy   = (const float*)d_in[2];
    const float* Wt0  = (const float*)d_in[3];
    const float* bt0  = (const float*)d_in[4];
    const float* Wt1  = (const float*)d_in[5];
    const float* bt1  = (const float*)d_in[6];
    const float* Wyu0 = (const float*)d_in[7];
    const float* byu0 = (const float*)d_in[8];
    const float* Wy0  = (const float*)d_in[9];
    const float* Wu0  = (const float*)d_in[10];
    const float* b0   = (const float*)d_in[11];
    const float* Wzu1 = (const float*)d_in[12];
    const float* bzu1 = (const float*)d_in[13];
    const float* Wz1  = (const float*)d_in[14];
    const float* Wyu1 = (const float*)d_in[15];
    const float* byu1 = (const float*)d_in[16];
    const float* Wy1  = (const float*)d_in[17];
    const float* Wu1  = (const float*)d_in[18];
    const float* b1   = (const float*)d_in[19];
    const float* Wzu2 = (const float*)d_in[20];
    const float* bzu2 = (const float*)d_in[21];
    const float* Wz2  = (const float*)d_in[22];
    const float* Wyu2 = (const float*)d_in[23];
    const float* byu2 = (const float*)d_in[24];
    const float* Wy2  = (const float*)d_in[25];
    const float* Wu2  = (const float*)d_in[26];
    const float* b2   = (const float*)d_in[27];
    float* ws  = (float*)d_ws;
    float* out = (float*)d_out;

    k_s1<<<dim3(73, 8),  dim3(256), 0, stream>>>(X, Wt0, bt0, Wu0, b0, Wyu0, byu0, Wz1, ws);
    k_s2<<<dim3(13, 8), dim3(256), 0, stream>>>(Wt1, bt1, Wzu1, bzu1, Wu1, b1, Wyu1, byu1, ws);
    k_s3<<<dim3(5, 8),  dim3(256), 0, stream>>>(Yy, Wzu2, bzu2, Wz2, Wyu2, byu2, Wy2, Wu2, b2, ws);
    k_main<<<dim3(MM / 64, NN), dim3(256), 0, stream>>>(Uu, Wy0, Wy1, ws);
    k_lse<<<dim3(128), dim3(256), 0, stream>>>(ws, out);
}

// Round 8
// 175.270 us; speedup vs baseline: 1.2386x; 1.2386x over previous
//
#include <hip/hip_runtime.h>

// Problem dims
#define NN 128
#define MM 2048
#define EPSF 0.01f

typedef __bf16 bf16x8 __attribute__((ext_vector_type(8)));
typedef __bf16 bf16x4 __attribute__((ext_vector_type(4)));
typedef float  f32x4  __attribute__((ext_vector_type(4)));

// Workspace layout (float offsets), total 1510528 floats = 6.04 MB
#define WS_SLACK 0            // [n][m] fp32
#define WS_W2    262144       // [n][256] fp32 gz2*softplus(Wz2)
#define WS_GZ1   294912       // [n][256] fp32
#define WS_YV    327680       // [n][8]  fp32 Y - gy2*Wy2
#define WS_CU2   328704       // [n]     fp32
#define WS_WTF   328832       // bf16 fragment-linear softplus(Wz1):
                              //   [kt=k/16][ch=z/32][lane][8], lane=q*16+c,
                              //   element = WTB[kt*16+c][ch*32+q*8+j]
#define WS_A2    361600       // bf16 [2048 m][32] = [U | 1 | 0...]
#define WS_B2    394368       // bf16 [128 n][256 z][32] = [gy0*Wy0 | c0 | 0...]
#define WS_BX    918656       // bf16 [128 n][256 k][32] = [gy1*Wy1 | c1 | 0...]
#define WS_U1    1442944      // bf16 [128 n][256]
#define WS_U2    1459328      // bf16 [128 n][256]
#define WS_C0    1475712      // bf16 [128 n][256]
#define WS_C1    1492096      // bf16 [128 n][256]
#define WS_GY0   1508480      // fp32 [128 n][8]
#define WS_GY1   1509504      // fp32 [128 n][8]

__device__ __forceinline__ float softplusf(float x) {
    return x > 20.f ? x : log1pf(expf(x));
}

__device__ __forceinline__ bf16x8 ld_cvt8(const float* __restrict__ p) {
    const float4* p4 = (const float4*)p;
    float4 a = p4[0], b = p4[1];
    bf16x8 r;
    r[0] = (__bf16)a.x; r[1] = (__bf16)a.y; r[2] = (__bf16)a.z; r[3] = (__bf16)a.w;
    r[4] = (__bf16)b.x; r[5] = (__bf16)b.y; r[6] = (__bf16)b.z; r[7] = (__bf16)b.w;
    return r;
}

// ---------------------------------------------------------------------------
// Level 1: K=64 over X. 33 col-tiles: [0,16)=Wt0->u1, [16,32)=Wu0->c0, 32=Wyu0->gy0
// ---------------------------------------------------------------------------
__global__ __launch_bounds__(256) void k_l1(
    const float* __restrict__ X,
    const float* __restrict__ Wt0, const float* __restrict__ bt0,
    const float* __restrict__ Wu0, const float* __restrict__ b0,
    const float* __restrict__ Wyu0, const float* __restrict__ byu0,
    float* __restrict__ ws)
{
    const int t = threadIdx.x, w = t >> 6, lane = t & 63;
    const int c = lane & 15, q = lane >> 4;
    const int nb = blockIdx.y * 16;
    const int ct = blockIdx.x * 4 + w;
    if (ct >= 33) return;

    bf16x8 a1[2];
#pragma unroll
    for (int ch = 0; ch < 2; ++ch)
        a1[ch] = ld_cvt8(X + (nb + c) * 64 + ch * 32 + q * 8);

    const float* rp;
    int col;
    if (ct < 16)      { col = ct * 16 + c;        rp = Wt0 + col * 64; }
    else if (ct < 32) { col = (ct - 16) * 16 + c; rp = Wu0 + col * 64; }
    else              { col = c & 7;              rp = Wyu0 + col * 64; }

    f32x4 D = {0.f, 0.f, 0.f, 0.f};
#pragma unroll
    for (int ch = 0; ch < 2; ++ch) {
        bf16x8 b = ld_cvt8(rp + ch * 32 + q * 8);
        D = __builtin_amdgcn_mfma_f32_16x16x32_bf16(a1[ch], b, D, 0, 0, 0);
    }

    if (ct < 16) {
        __bf16* u1p = (__bf16*)(ws + WS_U1);
        const float bv = bt0[col];
#pragma unroll
        for (int r = 0; r < 4; ++r)
            u1p[(nb + 4 * q + r) * 256 + col] = (__bf16)fmaxf(D[r] + bv, 0.f);
    } else if (ct < 32) {
        __bf16* c0p = (__bf16*)(ws + WS_C0);
        const float bv = b0[col];
#pragma unroll
        for (int r = 0; r < 4; ++r)
            c0p[(nb + 4 * q + r) * 256 + col] = (__bf16)(D[r] + bv);
    } else if (c < 8) {
        const float bv = byu0[c];
#pragma unroll
        for (int r = 0; r < 4; ++r)
            ws[WS_GY0 + (nb + 4 * q + r) * 8 + c] = D[r] + bv;
    }
}

// ---------------------------------------------------------------------------
// Level 2: K=256 over u1 (bf16). 49 tiles: Wt1->u2 | Wzu1->gz1 | Wu1->c1 | Wyu1->gy1
// ---------------------------------------------------------------------------
__global__ __launch_bounds__(256) void k_l2(
    const float* __restrict__ Wt1, const float* __restrict__ bt1,
    const float* __restrict__ Wzu1, const float* __restrict__ bzu1,
    const float* __restrict__ Wu1, const float* __restrict__ b1,
    const float* __restrict__ Wyu1, const float* __restrict__ byu1,
    float* __restrict__ ws)
{
    const int t = threadIdx.x, w = t >> 6, lane = t & 63;
    const int c = lane & 15, q = lane >> 4;
    const int nb = blockIdx.y * 16;
    const int ct = blockIdx.x * 4 + w;
    if (ct >= 49) return;

    const __bf16* u1p = (const __bf16*)(ws + WS_U1);
    bf16x8 aF[8];
#pragma unroll
    for (int ch = 0; ch < 8; ++ch)
        aF[ch] = *(const bf16x8*)(u1p + (nb + c) * 256 + ch * 32 + q * 8);

    const float* rp;
    int col;
    if (ct < 16)      { col = ct * 16 + c;        rp = Wt1 + col * 256; }
    else if (ct < 32) { col = (ct - 16) * 16 + c; rp = Wzu1 + col * 256; }
    else if (ct < 48) { col = (ct - 32) * 16 + c; rp = Wu1 + col * 256; }
    else              { col = c & 7;              rp = Wyu1 + col * 256; }

    f32x4 D = {0.f, 0.f, 0.f, 0.f};
#pragma unroll
    for (int ch = 0; ch < 8; ++ch) {
        bf16x8 b = ld_cvt8(rp + ch * 32 + q * 8);
        D = __builtin_amdgcn_mfma_f32_16x16x32_bf16(aF[ch], b, D, 0, 0, 0);
    }

    if (ct < 16) {
        __bf16* u2p = (__bf16*)(ws + WS_U2);
        const float bv = bt1[col];
#pragma unroll
        for (int r = 0; r < 4; ++r)
            u2p[(nb + 4 * q + r) * 256 + col] = (__bf16)fmaxf(D[r] + bv, 0.f);
    } else if (ct < 32) {
        const float bv = bzu1[col];
#pragma unroll
        for (int r = 0; r < 4; ++r)
            ws[WS_GZ1 + (nb + 4 * q + r) * 256 + col] = fmaxf(D[r] + bv, 0.f);
    } else if (ct < 48) {
        __bf16* c1p = (__bf16*)(ws + WS_C1);
        const float bv = b1[col];
#pragma unroll
        for (int r = 0; r < 4; ++r)
            c1p[(nb + 4 * q + r) * 256 + col] = (__bf16)(D[r] + bv);
    } else if (c < 8) {
        const float bv = byu1[c];
#pragma unroll
        for (int r = 0; r < 4; ++r)
            ws[WS_GY1 + (nb + 4 * q + r) * 8 + c] = D[r] + bv;
    }
}

// ---------------------------------------------------------------------------
// Level 3: K=256 over u2 (bf16). 17 tiles: Wzu2->w2 | (Wyu2->yv, Wu2->cu2)
// ---------------------------------------------------------------------------
__global__ __launch_bounds__(256) void k_l3(
    const float* __restrict__ Y,
    const float* __restrict__ Wzu2, const float* __restrict__ bzu2,
    const float* __restrict__ Wz2,
    const float* __restrict__ Wyu2, const float* __restrict__ byu2,
    const float* __restrict__ Wy2,
    const float* __restrict__ Wu2, const float* __restrict__ b2,
    float* __restrict__ ws)
{
    const int t = threadIdx.x, w = t >> 6, lane = t & 63;
    const int c = lane & 15, q = lane >> 4;
    const int nb = blockIdx.y * 16;
    const int ct = blockIdx.x * 4 + w;
    if (ct >= 17) return;

    const __bf16* u2p = (const __bf16*)(ws + WS_U2);
    bf16x8 aF[8];
#pragma unroll
    for (int ch = 0; ch < 8; ++ch)
        aF[ch] = *(const bf16x8*)(u2p + (nb + c) * 256 + ch * 32 + q * 8);

    const float* rp;
    int col = 0;
    if (ct < 16) { col = ct * 16 + c; rp = Wzu2 + col * 256; }
    else         { rp = (c < 8) ? (Wyu2 + c * 256) : Wu2; }

    f32x4 D = {0.f, 0.f, 0.f, 0.f};
#pragma unroll
    for (int ch = 0; ch < 8; ++ch) {
        bf16x8 b = ld_cvt8(rp + ch * 32 + q * 8);
        D = __builtin_amdgcn_mfma_f32_16x16x32_bf16(aF[ch], b, D, 0, 0, 0);
    }

    if (ct < 16) {
        const float bv = bzu2[col];
        const float sp = softplusf(Wz2[col]);
#pragma unroll
        for (int r = 0; r < 4; ++r) {
            float gz2 = fmaxf(D[r] + bv, 0.f);
            ws[WS_W2 + (nb + 4 * q + r) * 256 + col] = gz2 * sp;
        }
    } else if (c < 8) {
        const float bv = byu2[c];
        const float wy2 = Wy2[c];
#pragma unroll
        for (int r = 0; r < 4; ++r) {
            const int n = nb + 4 * q + r;
            ws[WS_YV + n * 8 + c] = Y[n * 8 + c] - (D[r] + bv) * wy2;
        }
    } else if (c == 8) {
#pragma unroll
        for (int r = 0; r < 4; ++r)
            ws[WS_CU2 + nb + 4 * q + r] = D[r] + b2[0];
    }
}

// ---------------------------------------------------------------------------
// k_bmat: WTF fragment-linear cvt + A2 build + B2/BX row materialization.
// 256 blocks x 256 threads.
// ---------------------------------------------------------------------------
__global__ __launch_bounds__(256) void k_bmat(
    const float* __restrict__ Wz1, const float* __restrict__ U,
    const float* __restrict__ Wy0, const float* __restrict__ Wy1,
    float* __restrict__ ws)
{
    const int b = blockIdx.x, t = threadIdx.x;
    const int i = b * 256 + t;

    // WTF: fragment-linear softplus(Wz1). 65536 elements, first 16384 threads
    // handle 4 each (contiguous j -> contiguous source floats).
    if (b < 64) {
        const int o = i * 4;                 // j0 = o&7 in {0,4}
        const int j0 = o & 7;
        const int c  = (o >> 3) & 15;
        const int q  = (o >> 7) & 3;
        const int ch = (o >> 9) & 7;
        const int kt = o >> 12;
        const float* src = Wz1 + (kt * 16 + c) * 256 + ch * 32 + q * 8 + j0;
        float4 v = *(const float4*)src;
        bf16x4 r;
        r[0] = (__bf16)softplusf(v.x); r[1] = (__bf16)softplusf(v.y);
        r[2] = (__bf16)softplusf(v.z); r[3] = (__bf16)softplusf(v.w);
        *(bf16x4*)((__bf16*)(ws + WS_WTF) + o) = r;
    }
    {
        int m = i >> 5, cc = i & 31;
        float v = cc < 8 ? U[m * 8 + cc] : (cc == 8 ? 1.f : 0.f);
        ((__bf16*)(ws + WS_A2))[i] = (__bf16)v;
    }

    const int which = b >> 7, n = b & 127, z = t;
    const float* wy = (which ? Wy1 : Wy0) + z * 8;
    const float* gy = ws + (which ? WS_GY1 : WS_GY0) + n * 8;
    const __bf16* cp = (const __bf16*)(ws + (which ? WS_C1 : WS_C0)) + n * 256 + z;
    __bf16* dst = (__bf16*)(ws + (which ? WS_BX : WS_B2)) + (n * 256 + z) * 32;

    bf16x8 zz;
#pragma unroll
    for (int j = 0; j < 8; ++j) zz[j] = (__bf16)0.f;
    bf16x8 v0, v1 = zz;
#pragma unroll
    for (int d = 0; d < 8; ++d) v0[d] = (__bf16)(gy[d] * wy[d]);
    v1[0] = *cp;
    *(bf16x8*)(dst)      = v0;
    *(bf16x8*)(dst + 8)  = v1;
    *(bf16x8*)(dst + 16) = zz;
    *(bf16x8*)(dst + 24) = zz;
}

// ---------------------------------------------------------------------------
// k_main: round-6 structure; ONLY change = WTF fragment-linear B loads
// (1 KB fully-coalesced per load instead of 4 KB of touched lines).
// ---------------------------------------------------------------------------
__global__ __launch_bounds__(256, 4) void k_main(
    const float* __restrict__ U,
    float* __restrict__ ws)
{
    __shared__ __bf16 zh[64][264];   // +8 pad
    __shared__ float gz1s[256];
    __shared__ float w2s[256];
    __shared__ float sdot[64];
    __shared__ float psum[4][64];

    const int t  = threadIdx.x;
    const int n  = blockIdx.y;
    const int m0 = blockIdx.x * 64;
    const int w    = t >> 6;
    const int lane = t & 63;
    const int c = lane & 15;
    const int q = lane >> 4;

    gz1s[t] = ws[WS_GZ1 + n * 256 + t];
    w2s[t]  = ws[WS_W2  + n * 256 + t];
    if (t < 64) {
        float sd = 0.f;
#pragma unroll
        for (int d = 0; d < 8; ++d)
            sd += U[(m0 + t) * 8 + d] * ws[WS_YV + n * 8 + d];
        sdot[t] = sd;
    }

    const __bf16* A2p = (const __bf16*)(ws + WS_A2);
    const __bf16* B2p = (const __bf16*)(ws + WS_B2) + n * 8192;
    const __bf16* BXp = (const __bf16*)(ws + WS_BX) + n * 8192;
    const __bf16* WTF = (const __bf16*)(ws + WS_WTF);

    bf16x8 a2f[4];
#pragma unroll
    for (int mi = 0; mi < 4; ++mi)
        a2f[mi] = *(const bf16x8*)(A2p + (m0 + 16 * mi + c) * 32 + q * 8);

    // ---- pre-GEMM: D1[z][m], wave w covers z in [64w, 64w+64) ----
    {
        bf16x8 b2f[4];
#pragma unroll
        for (int zt = 0; zt < 4; ++zt)
            b2f[zt] = *(const bf16x8*)(B2p + (64 * w + 16 * zt + c) * 32 + q * 8);
        f32x4 pre[4][4];
#pragma unroll
        for (int zt = 0; zt < 4; ++zt)
#pragma unroll
            for (int mi = 0; mi < 4; ++mi) {
                f32x4 zacc = {0.f, 0.f, 0.f, 0.f};
                pre[zt][mi] = __builtin_amdgcn_mfma_f32_16x16x32_bf16(
                    b2f[zt], a2f[mi], zacc, 0, 0, 0);
            }
#pragma unroll
        for (int zt = 0; zt < 4; ++zt) {
            const int zb = 64 * w + 16 * zt + 4 * q;
#pragma unroll
            for (int mi = 0; mi < 4; ++mi) {
                bf16x4 v4;
#pragma unroll
                for (int r = 0; r < 4; ++r)
                    v4[r] = (__bf16)(fmaxf(pre[zt][mi][r], 0.f) * gz1s[zb + r]);
                *(bf16x4*)&zh[c + 16 * mi][zb] = v4;
            }
        }
    }

    // ---- main GEMM: D2[m][k], wave w covers k in [64w, 64w+64) ----
    f32x4 acc[4][4];
#pragma unroll
    for (int mi = 0; mi < 4; ++mi)
#pragma unroll
        for (int kj = 0; kj < 4; ++kj)
            acc[mi][kj] = f32x4{0.f, 0.f, 0.f, 0.f};

    __syncthreads();

    for (int ch = 0; ch < 8; ++ch) {
        bf16x8 az[4], bw[4];
#pragma unroll
        for (int mi = 0; mi < 4; ++mi)
            az[mi] = *(const bf16x8*)&zh[c + 16 * mi][ch * 32 + q * 8];
#pragma unroll
        for (int kj = 0; kj < 4; ++kj)
            bw[kj] = *(const bf16x8*)(WTF + ((4 * w + kj) * 8 + ch) * 512 + lane * 8);
#pragma unroll
        for (int mi = 0; mi < 4; ++mi)
#pragma unroll
            for (int kj = 0; kj < 4; ++kj)
                acc[mi][kj] = __builtin_amdgcn_mfma_f32_16x16x32_bf16(
                    az[mi], bw[kj], acc[mi][kj], 0, 0, 0);
    }
    // rank-1 chunk: [U|1] x [gy1*Wy1 | c1]
    {
        bf16x8 bx[4];
#pragma unroll
        for (int kj = 0; kj < 4; ++kj)
            bx[kj] = *(const bf16x8*)(BXp + (64 * w + 16 * kj + c) * 32 + q * 8);
#pragma unroll
        for (int mi = 0; mi < 4; ++mi)
#pragma unroll
            for (int kj = 0; kj < 4; ++kj)
                acc[mi][kj] = __builtin_amdgcn_mfma_f32_16x16x32_bf16(
                    a2f[mi], bx[kj], acc[mi][kj], 0, 0, 0);
    }

    // ---- epilogue: p[m] = sum_k relu(acc)*w2[k] ----
    float p[4][4];
#pragma unroll
    for (int mi = 0; mi < 4; ++mi)
#pragma unroll
        for (int r = 0; r < 4; ++r) p[mi][r] = 0.f;
#pragma unroll
    for (int kj = 0; kj < 4; ++kj) {
        float w2v = w2s[64 * w + 16 * kj + c];
#pragma unroll
        for (int mi = 0; mi < 4; ++mi)
#pragma unroll
            for (int r = 0; r < 4; ++r)
                p[mi][r] += fmaxf(acc[mi][kj][r], 0.f) * w2v;
    }
#pragma unroll
    for (int mi = 0; mi < 4; ++mi)
#pragma unroll
        for (int r = 0; r < 4; ++r) {
            float v = p[mi][r];
            v += __shfl_xor(v, 8);
            v += __shfl_xor(v, 4);
            v += __shfl_xor(v, 2);
            v += __shfl_xor(v, 1);
            p[mi][r] = v;
        }
    if (c == 0) {
#pragma unroll
        for (int mi = 0; mi < 4; ++mi)
            *(float4*)&psum[w][16 * mi + 4 * q] =
                make_float4(p[mi][0], p[mi][1], p[mi][2], p[mi][3]);
    }
    __syncthreads();
    if (t < 64) {
        float cu2 = ws[WS_CU2 + n];
        float pp = psum[0][t] + psum[1][t] + psum[2][t] + psum[3][t];
        ws[WS_SLACK + n * 2048 + m0 + t] = sdot[t] - cu2 - pp;
    }
}

// ---------------------------------------------------------------------------
// k_lse: per-n stable logsumexp over m -> psi[n]
// ---------------------------------------------------------------------------
__global__ __launch_bounds__(256) void k_lse(const float* __restrict__ ws,
                                             float* __restrict__ out) {
    __shared__ float redmax[4];
    __shared__ float redsum[4];
    const int n = blockIdx.x;
    const int t = threadIdx.x;
    const float* s = ws + WS_SLACK + n * 2048;

    float vals[8];
    float mx = -3.4e38f;
#pragma unroll
    for (int i = 0; i < 8; ++i) {
        vals[i] = s[t + 256 * i];
        mx = fmaxf(mx, vals[i]);
    }
#pragma unroll
    for (int off = 32; off; off >>= 1) mx = fmaxf(mx, __shfl_xor(mx, off));
    if ((t & 63) == 0) redmax[t >> 6] = mx;
    __syncthreads();
    mx = fmaxf(fmaxf(redmax[0], redmax[1]), fmaxf(redmax[2], redmax[3]));

    float sum = 0.f;
#pragma unroll
    for (int i = 0; i < 8; ++i) sum += expf((vals[i] - mx) * (1.f / EPSF));
#pragma unroll
    for (int off = 32; off; off >>= 1) sum += __shfl_xor(sum, off);
    if ((t & 63) == 0) redsum[t >> 6] = sum;
    __syncthreads();
    if (t == 0) {
        float S = redsum[0] + redsum[1] + redsum[2] + redsum[3];
        out[n] = EPSF * logf(S * (1.f / 2048.f)) + mx;
    }
}

// ---------------------------------------------------------------------------
extern "C" void kernel_launch(void* const* d_in, const int* in_sizes, int n_in,
                              void* d_out, int out_size, void* d_ws, size_t ws_size,
                              hipStream_t stream) {
    const float* X    = (const float*)d_in[0];
    const float* Uu   = (const float*)d_in[1];
    const float* Yy   = (const float*)d_in[2];
    const float* Wt0  = (const float*)d_in[3];
    const float* bt0  = (const float*)d_in[4];
    const float* Wt1  = (const float*)d_in[5];
    const float* bt1  = (const float*)d_in[6];
    const float* Wyu0 = (const float*)d_in[7];
    const float* byu0 = (const float*)d_in[8];
    const float* Wy0  = (const float*)d_in[9];
    const float* Wu0  = (const float*)d_in[10];
    const float* b0   = (const float*)d_in[11];
    const float* Wzu1 = (const float*)d_in[12];
    const float* bzu1 = (const float*)d_in[13];
    const float* Wz1  = (const float*)d_in[14];
    const float* Wyu1 = (const float*)d_in[15];
    const float* byu1 = (const float*)d_in[16];
    const float* Wy1  = (const float*)d_in[17];
    const float* Wu1  = (const float*)d_in[18];
    const float* b1   = (const float*)d_in[19];
    const float* Wzu2 = (const float*)d_in[20];
    const float* bzu2 = (const float*)d_in[21];
    const float* Wz2  = (const float*)d_in[22];
    const float* Wyu2 = (const float*)d_in[23];
    const float* byu2 = (const float*)d_in[24];
    const float* Wy2  = (const float*)d_in[25];
    const float* Wu2  = (const float*)d_in[26];
    const float* b2   = (const float*)d_in[27];
    float* ws  = (float*)d_ws;
    float* out = (float*)d_out;

    k_l1<<<dim3(9, 8),  dim3(256), 0, stream>>>(X, Wt0, bt0, Wu0, b0, Wyu0, byu0, ws);
    k_l2<<<dim3(13, 8), dim3(256), 0, stream>>>(Wt1, bt1, Wzu1, bzu1, Wu1, b1, Wyu1, byu1, ws);
    k_l3<<<dim3(5, 8),  dim3(256), 0, stream>>>(Yy, Wzu2, bzu2, Wz2, Wyu2, byu2, Wy2, Wu2, b2, ws);
    k_bmat<<<dim3(256), dim3(256), 0, stream>>>(Wz1, Uu, Wy0, Wy1, ws);
    k_main<<<dim3(MM / 64, NN), dim3(256), 0, stream>>>(Uu, ws);
    k_lse<<<dim3(128), dim3(256), 0, stream>>>(ws, out);
}